// Round 11
// baseline (1523.783 us; speedup 1.0000x reference)
//
#include <hip/hip_runtime.h>
#include <hip/hip_bf16.h>
#include <math.h>

#define S_ 2048
#define DM_ 2048

// Full-wave (64-lane) sum via DPP row_shr/row_bcast, broadcast via readlane.
__device__ __forceinline__ float wave_reduce_add_f32(float x) {
  float t;
  t = __int_as_float(__builtin_amdgcn_update_dpp(0, __float_as_int(x), 0x111, 0xf, 0xf, true)); x += t;
  t = __int_as_float(__builtin_amdgcn_update_dpp(0, __float_as_int(x), 0x112, 0xf, 0xf, true)); x += t;
  t = __int_as_float(__builtin_amdgcn_update_dpp(0, __float_as_int(x), 0x114, 0xf, 0xf, true)); x += t;
  t = __int_as_float(__builtin_amdgcn_update_dpp(0, __float_as_int(x), 0x118, 0xf, 0xf, true)); x += t;
  t = __int_as_float(__builtin_amdgcn_update_dpp(0, __float_as_int(x), 0x142, 0xa, 0xf, true)); x += t;
  t = __int_as_float(__builtin_amdgcn_update_dpp(0, __float_as_int(x), 0x143, 0xc, 0xf, true)); x += t;
  return __int_as_float(__builtin_amdgcn_readlane(__float_as_int(x), 63));
}

__device__ __forceinline__ float rdlane(float x, int l) {
  return __int_as_float(__builtin_amdgcn_readlane(__float_as_int(x), l));
}

// ---------------------------------------------------------------------------
// K1: fused projections. proj row (stride 256): k(l2)@0 | v@64 | q(l2)@128 |
// a@192. Scalar qw[row] stored separately (kept; harmless). (baseline-proven)
// ---------------------------------------------------------------------------
__global__ __launch_bounds__(256) void k_proj(
    const float* __restrict__ x, const float* __restrict__ Wk,
    const float* __restrict__ Wv, const float* __restrict__ Wq,
    const float* __restrict__ Wa, const float* __restrict__ Wab,
    const float* __restrict__ lam, float* __restrict__ proj,
    float* __restrict__ qwArr)
{
  __shared__ __align__(16) float xs[16 * 40];
  __shared__ __align__(16) float ws[32 * 260];
  const int tid = threadIdx.x;
  const int r0  = blockIdx.x * 16;
  const int ct  = tid & 63;
  const int rt  = tid >> 6;
  float acc[4][4];
  #pragma unroll
  for (int r = 0; r < 4; r++) { acc[r][0] = 0.f; acc[r][1] = 0.f; acc[r][2] = 0.f; acc[r][3] = 0.f; }

  const int sg = tid >> 3;
  const int sm = tid & 7;
  const float* wbase[4] = {Wk, Wv, Wq, Wa};

  for (int k0 = 0; k0 < DM_; k0 += 32) {
    if (tid < 128) {
      const int rr = tid >> 3;
      const int ko = (tid & 7) << 2;
      float4 xv = *(const float4*)(x + (size_t)(r0 + rr) * DM_ + k0 + ko);
      *(float4*)(xs + rr * 40 + ko) = xv;
    }
    #pragma unroll
    for (int p = 0; p < 8; p++) {
      const int c = sg + p * 32;
      const float* wb = wbase[p >> 1];
      const int cc = c - (p >> 1) * 64;
      float4 wv = *(const float4*)(wb + (size_t)cc * DM_ + k0 + sm * 4);
      ws[(sm * 4 + 0) * 260 + c] = wv.x;
      ws[(sm * 4 + 1) * 260 + c] = wv.y;
      ws[(sm * 4 + 2) * 260 + c] = wv.z;
      ws[(sm * 4 + 3) * 260 + c] = wv.w;
    }
    __syncthreads();
    #pragma unroll
    for (int kq = 0; kq < 8; kq++) {
      float4 xv[4];
      #pragma unroll
      for (int r = 0; r < 4; r++) xv[r] = *(const float4*)(xs + (rt * 4 + r) * 40 + kq * 4);
      #pragma unroll
      for (int i = 0; i < 4; i++) {
        const int kk = kq * 4 + i;
        float wv0 = ws[kk * 260 + ct];
        float wv1 = ws[kk * 260 + ct + 64];
        float wv2 = ws[kk * 260 + ct + 128];
        float wv3 = ws[kk * 260 + ct + 192];
        #pragma unroll
        for (int r = 0; r < 4; r++) {
          float xr = (i == 0) ? xv[r].x : (i == 1) ? xv[r].y : (i == 2) ? xv[r].z : xv[r].w;
          acc[r][0] = fmaf(xr, wv0, acc[r][0]);
          acc[r][1] = fmaf(xr, wv1, acc[r][1]);
          acc[r][2] = fmaf(xr, wv2, acc[r][2]);
          acc[r][3] = fmaf(xr, wv3, acc[r][3]);
        }
      }
    }
    __syncthreads();
  }
  float lamv = lam[ct];
  float la = logf(1.f / (1.f + expf(-lamv)) + 1e-8f);
  float bv = Wab[ct];
  #pragma unroll
  for (int r = 0; r < 4; r++) {
    float nk = wave_reduce_add_f32(acc[r][0] * acc[r][0]);
    float nq = wave_reduce_add_f32(acc[r][2] * acc[r][2]);
    nk = fmaxf(sqrtf(nk), 1e-12f);
    nq = fmaxf(sqrtf(nq), 1e-12f);
    float pre = acc[r][3] + bv;
    float rr_ = 1.f / (1.f + expf(-pre));
    float al  = expf(8.f * rr_ * la);
    float kn  = acc[r][0] / nk;
    float qn  = acc[r][2] / nq;
    float qw  = wave_reduce_add_f32(qn * (1.f - al) * kn);
    float* pr = proj + (size_t)(r0 + rt * 4 + r) * 256;
    pr[ct]        = kn;
    pr[64 + ct]   = acc[r][1];
    pr[128 + ct]  = qn;
    pr[192 + ct]  = al;
    if (ct == 0) qwArr[r0 + rt * 4 + r] = qw;
  }
}

// ---------------------------------------------------------------------------
// K1b: per-row cross-step scalars only (128 KB total):
//   scArr[row*4 + {0,1,2,3}] = cq_t = q_t.w_{t-1}, ck_t = k_t.w_{t-1},
//                              cy_t = (q_t a_t).w_{t-1}, qw_t = q_t.w_t
// with w_t = (1-a_t) k_t; t=0 -> w_{-1}=0 (first three scalars 0).
// ---------------------------------------------------------------------------
__global__ __launch_bounds__(256) void k_coef(const float* __restrict__ proj,
                                              float* __restrict__ scArr)
{
  const int row  = blockIdx.x * 4 + (threadIdx.x >> 6);
  const int lane = threadIdx.x & 63;
  const int t = row & (S_ - 1);
  const float* pr = proj + (size_t)row * 256;
  float kn = pr[lane];
  float qn = pr[128 + lane];
  float al = pr[192 + lane];
  float wprev = 0.f;
  if (t > 0) {
    const float* pp = pr - 256;
    wprev = (1.f - pp[192 + lane]) * pp[lane];
  }
  float w  = (1.f - al) * kn;
  float cq = wave_reduce_add_f32(qn * wprev);
  float ck = wave_reduce_add_f32(kn * wprev);
  float cy = wave_reduce_add_f32(qn * al * wprev);
  float qw = wave_reduce_add_f32(qn * w);
  if (lane == 0) *(float4*)(scArr + (size_t)row * 4) = make_float4(cq, ck, cy, qw);
}

// ---------------------------------------------------------------------------
// K2: sequential scan, recurrence-hoisted, baseline-proven staging.
// 1 block/batch, 4 waves x 16 H-rows, lane = v-column. Serial chain per step:
//   xch-read -> pred=fma(cq,gP,D1) -> d^2 -> DPP reduce -> sigmoid -> g
// Dots for step t+1 (coefficients c1=q_{t+1}a_t, c2=k_{t+1}a_t, c3=c1*a_{t+1}
// computed in-register from nxt/cur) run over H_{t-1} in the chain's shadow,
// exchanged via LDS, consumed next call. y_t = D3 + cy*gP + qw*g (wave-0
// scalar term; cross-wave D3 sum deferred to k_out). One barrier per step.
// ---------------------------------------------------------------------------
struct KQA { float4 k[4], q[4], a[4]; float v; };

__device__ __forceinline__ void load_kqa(const float* __restrict__ slot,
                                         int w, int lane, KQA& s) {
  const float4* s4 = (const float4*)slot;
  const int o = w * 4;
  #pragma unroll
  for (int i = 0; i < 4; i++) {
    s.k[i] = s4[o + i];         // k @ floats 0   (wave-uniform broadcast)
    s.q[i] = s4[32 + o + i];    // q @ floats 128
    s.a[i] = s4[48 + o + i];    // a @ floats 192
  }
  s.v = slot[64 + lane];        // v @ floats 64, per-lane
}

__device__ __forceinline__ void sstep(int t, float4 sc, float* __restrict__ inv,
    const float2* __restrict__ xchR, float2* __restrict__ xchW,
    float* __restrict__ yb, const float* __restrict__ pb,
    float H[16], KQA& cur, KQA& nxt, float& d3c, float& gP,
    float& pf, int w, int lane, int tid, float qwSel)
{
  // finish step t: D1/D2 partials were exchanged last call (fenced by its barrier)
  float2 x0 = xchR[lane], x1 = xchR[64 + lane], x2 = xchR[128 + lane], x3 = xchR[192 + lane];
  float D1f = (x0.x + x1.x) + (x2.x + x3.x);
  float D2f = (x0.y + x1.y) + (x2.y + x3.y);
  float pred = fmaf(sc.x, gP, D1f);           // q_t.H_{t-1} = D1 + cq_t g_{t-1}
  float kh   = fmaf(sc.y, gP, D2f);           // k_t.H_{t-1} = D2 + ck_t g_{t-1}
  float d = cur.v - pred;
  float e = wave_reduce_add_f32(d * d);
  float sg = __builtin_amdgcn_rcpf(1.f + __builtin_amdgcn_exp2f(e * -1.4426936f));
  float g = sg * (cur.v - kh);
  // y_t per-wave partial: D3 partial + (once) cy_t g_{t-1} + qw_t g_t
  yb[(size_t)t * 256 + tid] = d3c + qwSel * fmaf(sc.z, gP, sc.w * g);
  // staging (baseline-proven): ring write slot t+2, prefetch row t+4
  inv[(((t + 2) & 3) << 8) + tid] = pf;
  pf = pb[(size_t)min(t + 4, S_ - 1) * 256 + tid];
  // next step's inputs (slot t+1; written at call t-1, fenced)
  load_kqa(inv + (((t + 1) & 3) << 8), w, lane, nxt);
  // dots for step t+1 over H_{t-1} (H not yet updated)
  float dA = 0.f, dB = 0.f, kA = 0.f, kB = 0.f, yA = 0.f, yB = 0.f;
  #pragma unroll
  for (int j = 0; j < 4; j++) {
    float c1, c2, c3;
    c1 = nxt.q[j].x * cur.a[j].x; c2 = nxt.k[j].x * cur.a[j].x; c3 = c1 * nxt.a[j].x;
    dA = fmaf(c1, H[4*j+0], dA); kA = fmaf(c2, H[4*j+0], kA); yA = fmaf(c3, H[4*j+0], yA);
    c1 = nxt.q[j].y * cur.a[j].y; c2 = nxt.k[j].y * cur.a[j].y; c3 = c1 * nxt.a[j].y;
    dB = fmaf(c1, H[4*j+1], dB); kB = fmaf(c2, H[4*j+1], kB); yB = fmaf(c3, H[4*j+1], yB);
    c1 = nxt.q[j].z * cur.a[j].z; c2 = nxt.k[j].z * cur.a[j].z; c3 = c1 * nxt.a[j].z;
    dA = fmaf(c1, H[4*j+2], dA); kA = fmaf(c2, H[4*j+2], kA); yA = fmaf(c3, H[4*j+2], yA);
    c1 = nxt.q[j].w * cur.a[j].w; c2 = nxt.k[j].w * cur.a[j].w; c3 = c1 * nxt.a[j].w;
    dB = fmaf(c1, H[4*j+3], dB); kB = fmaf(c2, H[4*j+3], kB); yB = fmaf(c3, H[4*j+3], yB);
  }
  d3c = yA + yB;
  xchW[(w << 6) + lane] = make_float2(dA + dB, kA + kB);
  // H_t = a_t H_{t-1} + (1-a_t) k_t g_t
  #pragma unroll
  for (int j = 0; j < 4; j++) {
    float wx = (1.f - cur.a[j].x) * cur.k[j].x;
    float wy = (1.f - cur.a[j].y) * cur.k[j].y;
    float wz = (1.f - cur.a[j].z) * cur.k[j].z;
    float ww = (1.f - cur.a[j].w) * cur.k[j].w;
    H[4*j+0] = fmaf(cur.a[j].x, H[4*j+0], wx * g);
    H[4*j+1] = fmaf(cur.a[j].y, H[4*j+1], wy * g);
    H[4*j+2] = fmaf(cur.a[j].z, H[4*j+2], wz * g);
    H[4*j+3] = fmaf(cur.a[j].w, H[4*j+3], ww * g);
  }
  asm volatile("s_waitcnt lgkmcnt(0)\n\ts_barrier" ::: "memory");
  gP = g;
}

__global__ __launch_bounds__(256, 1) void k_scan(const float* __restrict__ proj,
    const float* __restrict__ scArr, float* __restrict__ ypart)
{
  __shared__ __align__(16) float inv[4 * 256];     // 4-slot input ring
  __shared__ __align__(16) float2 xch[2][256];     // ping-pong exchange
  const int b = blockIdx.x, tid = threadIdx.x;
  const int w = tid >> 6, lane = tid & 63;
  const float* pb  = proj + (size_t)b * S_ * 256;
  const float4* scb = (const float4*)scArr + (size_t)b * S_;
  float* yb = ypart + (size_t)b * S_ * 256;
  float H[16];
  #pragma unroll
  for (int j = 0; j < 16; j++) H[j] = 0.f;
  float gP = 0.f, d3c = 0.f;
  // prologue: zero xch[0] (dots_0 over H_{-2}=0), slots 0,1 in LDS, rows 2,3 in regs
  xch[0][tid] = make_float2(0.f, 0.f);
  inv[tid]       = pb[tid];
  inv[256 + tid] = pb[256 + tid];
  float pfE = pb[2 * 256 + tid];
  float pfO = pb[3 * 256 + tid];
  __syncthreads();
  const float qwSel = (w == 0) ? 1.f : 0.f;
  KQA curA, curB;
  load_kqa(inv, w, lane, curA);   // step-0 inputs
  for (int t0 = 0; t0 < S_; t0 += 64) {
    float4 scv = scb[t0 + lane];  // 64 steps' scalars, one float4 per lane
    for (int tt = 0; tt < 64; tt += 2) {
      float4 s0 = make_float4(rdlane(scv.x, tt),     rdlane(scv.y, tt),
                              rdlane(scv.z, tt),     rdlane(scv.w, tt));
      float4 s1 = make_float4(rdlane(scv.x, tt + 1), rdlane(scv.y, tt + 1),
                              rdlane(scv.z, tt + 1), rdlane(scv.w, tt + 1));
      sstep(t0 + tt,     s0, inv, xch[0], xch[1], yb, pb, H, curA, curB, d3c, gP, pfE, w, lane, tid, qwSel);
      sstep(t0 + tt + 1, s1, inv, xch[1], xch[0], yb, pb, H, curB, curA, d3c, gP, pfO, w, lane, tid, qwSel);
    }
  }
}

// ---------------------------------------------------------------------------
// Wo transpose (2048x64 -> 64x2048).
// ---------------------------------------------------------------------------
__global__ __launch_bounds__(256) void k_trans(const float* __restrict__ Wo,
                                               float* __restrict__ WoT) {
  int i = blockIdx.x * 256 + threadIdx.x;
  int d = i >> 11;
  int c = i & 2047;
  WoT[i] = Wo[(size_t)c * 64 + d];
}

// ---------------------------------------------------------------------------
// K3: sum y-partials, RMS-norm over 64, * norm_w, then yn @ Wo^T. (unchanged)
// ---------------------------------------------------------------------------
__global__ __launch_bounds__(256) void k_out(const float* __restrict__ ypart,
    const float* __restrict__ norm_w, const float* __restrict__ WoT,
    float* __restrict__ out)
{
  __shared__ __align__(16) float yn[16 * 64];
  const int tid = threadIdx.x;
  const int r0  = blockIdx.x * 16;
  const int c0  = blockIdx.y * 512;
  {
    const int r = tid >> 4;
    const int d = (tid & 15) * 4;
    const float* yp = ypart + (size_t)(r0 + r) * 256;
    float4 y0 = *(const float4*)(yp + d);
    float4 y1 = *(const float4*)(yp + 64 + d);
    float4 y2 = *(const float4*)(yp + 128 + d);
    float4 y3 = *(const float4*)(yp + 192 + d);
    float yx = y0.x + y1.x + y2.x + y3.x;
    float yy = y0.y + y1.y + y2.y + y3.y;
    float yz = y0.z + y1.z + y2.z + y3.z;
    float yw = y0.w + y1.w + y2.w + y3.w;
    float sq = yx * yx + yy * yy + yz * yz + yw * yw;
    sq += __shfl_xor(sq, 1, 64);
    sq += __shfl_xor(sq, 2, 64);
    sq += __shfl_xor(sq, 4, 64);
    sq += __shfl_xor(sq, 8, 64);
    float rms = rsqrtf(sq * (1.f / 64.f) + 1e-6f);
    float4 nw = *(const float4*)(norm_w + d);
    yn[r * 64 + d + 0] = yx * rms * nw.x;
    yn[r * 64 + d + 1] = yy * rms * nw.y;
    yn[r * 64 + d + 2] = yz * rms * nw.z;
    yn[r * 64 + d + 3] = yw * rms * nw.w;
  }
  __syncthreads();
  const int ctq = tid & 127;
  const int rt  = tid >> 7;
  float acc[8][4];
  #pragma unroll
  for (int r = 0; r < 8; r++) { acc[r][0] = 0.f; acc[r][1] = 0.f; acc[r][2] = 0.f; acc[r][3] = 0.f; }
  #pragma unroll 8
  for (int d = 0; d < 64; d++) {
    float4 wv = *(const float4*)(WoT + (size_t)d * 2048 + c0 + ctq * 4);
    #pragma unroll
    for (int r = 0; r < 8; r++) {
      float yv = yn[(rt * 8 + r) * 64 + d];
      acc[r][0] = fmaf(yv, wv.x, acc[r][0]);
      acc[r][1] = fmaf(yv, wv.y, acc[r][1]);
      acc[r][2] = fmaf(yv, wv.z, acc[r][2]);
      acc[r][3] = fmaf(yv, wv.w, acc[r][3]);
    }
  }
  #pragma unroll
  for (int r = 0; r < 8; r++) {
    float4 o; o.x = acc[r][0]; o.y = acc[r][1]; o.z = acc[r][2]; o.w = acc[r][3];
    *(float4*)(out + (size_t)(r0 + rt * 8 + r) * 2048 + c0 + ctq * 4) = o;
  }
}

extern "C" void kernel_launch(void* const* d_in, const int* in_sizes, int n_in,
                              void* d_out, int out_size, void* d_ws, size_t ws_size,
                              hipStream_t stream) {
  const float* x   = (const float*)d_in[0];
  const float* Wk  = (const float*)d_in[1];
  const float* Wv  = (const float*)d_in[2];
  const float* Wq  = (const float*)d_in[3];
  const float* Wa  = (const float*)d_in[4];
  const float* Wab = (const float*)d_in[5];
  const float* lam = (const float*)d_in[6];
  const float* nw  = (const float*)d_in[7];
  const float* Wo  = (const float*)d_in[8];
  float* out = (float*)d_out;

  float* wsf   = (float*)d_ws;
  float* proj  = wsf;                 // 4*2048*256 = 2,097,152 floats
  float* ypart = wsf + 2097152;       // 4*2048*256 = 2,097,152 floats
  float* WoT   = wsf + 4194304;       // 64*2048    =   131,072 floats
  float* qwArr = wsf + 4325376;       // 4*2048     =     8,192 floats
  float* scArr = wsf + 4333568;       // 4*2048*4   =    32,768 floats (17.47 MB total)

  k_trans<<<dim3(512), dim3(256), 0, stream>>>(Wo, WoT);
  k_proj <<<dim3(512), dim3(256), 0, stream>>>(x, Wk, Wv, Wq, Wa, Wab, lam, proj, qwArr);
  k_coef <<<dim3(2048), dim3(256), 0, stream>>>(proj, scArr);
  k_scan <<<dim3(4),   dim3(256), 0, stream>>>(proj, scArr, ypart);
  k_out  <<<dim3(512, 4), dim3(256), 0, stream>>>(ypart, nw, WoT, out);
}